// Round 7
// baseline (800.596 us; speedup 1.0000x reference)
//
#include <hip/hip_runtime.h>

// LSTM RNN_20263655702953 — MI355X (gfx950), round 7.
//
// Reference quirk: hs[:, -1, :] selects BATCH index 511 => single sequential
// LSTM chain (1024 steps, H=64), then (1024,64)@(64,2) projection.
//
// R7: SINGLE WAVE + f16 MFMA. Evidence: R4/R6 (4-wave fp32) stall ~600cyc on
// the cross-wave exchange; R5 (1-wave fp32) is issue-bound at 512+ cyc
// (32 lanes x 1 FMA/cyc floor). MFMA does the k-reduction inside the pipe:
// G = W(256x64)@h as 16 row-tiles x 2 k-halves = 32 mfma_f32_16x16x32_f16
// (~154 issue cyc), h replicated across all 16 B-cols. Single wave => NO
// barriers; all LDS traffic is same-wave (DS FIFO ordering).
//   B-frag: h as f16 in 128B LDS; lane reads ds_read_b128 at quad*16.
//   Epilogue: C/D layout col=lane&15,row=quad*4+reg => col-0 lanes hold all
//   16 tiles in compile-time regs; 16 exec-masked ds_write_b128 scatter to
//   glds[gate][unit] (padded stride 72 vs bank conflicts), then every lane
//   reads its unit's 4 gates (consecutive addr, conflict-free).
//   bias + W_ih@x_t folded after the read (precomputed during MFMA phase).
// Precision: f16 mantissa 2^-11; |W|<=0.125,|h|<=1 => gate err ~3e-4,
// h drift ~5e-4 << 3.96e-3 threshold. Fallback: h hi/lo split across
// even/odd B-cols (zero extra MFMAs) if absmax complains.

typedef _Float16 f16;
typedef _Float16 f16x8 __attribute__((ext_vector_type(8)));
typedef float    f32x4 __attribute__((ext_vector_type(4)));

#define T_LEN 1024
#define BATCH 512
#define HID   64

__device__ __forceinline__ float fast_rcp(float x) {
    return __builtin_amdgcn_rcpf(x);  // v_rcp_f32, ~1e-7 rel err
}
__device__ __forceinline__ float fast_sigmoid(float x) {
    return fast_rcp(1.0f + __expf(-x));
}
__device__ __forceinline__ float fast_tanh(float x) {
    // 1 - 2/(e^{2x}+1); saturates correctly for |x| large
    return 1.0f - 2.0f * fast_rcp(__expf(2.0f * x) + 1.0f);
}

__global__ __launch_bounds__(64, 1)
void lstm_seq_kernel(const float* __restrict__ x,
                     const float* __restrict__ W_ih,
                     const float* __restrict__ W_hh,
                     const float* __restrict__ b_ih,
                     const float* __restrict__ b_hh,
                     const float* __restrict__ W_fc,
                     const float* __restrict__ b_fc,
                     float* __restrict__ out,
                     float* __restrict__ hist)   // d_ws: 1024*64 floats
{
    __shared__ __align__(16) float xs[2 * T_LEN];   // 8 KB: x[:,511,:]
    __shared__ __align__(16) f16   hfrag[2][HID];   // 256 B: h in f16, dbuf
    __shared__ __align__(16) float glds[2][4][72];  // 2.25 KB: G exchange [buf][gate][unit], padded

    const int lane = threadIdx.x;   // 0..63
    const int qd   = lane >> 4;     // quad-row group 0..3 (A/B k-block, C row-block)
    const int cl   = lane & 15;     // col 0..15 (A m-row, C col)

    // ---- stage x[:,511,:] into LDS (one-time; same-wave => no barrier)
    for (int j = 0; j < 16; ++j) {
        const int t = lane + 64 * j;
        const float2 v = *(const float2*)(x + (size_t)(t * BATCH + (BATCH - 1)) * 2);
        xs[2 * t]     = v.x;
        xs[2 * t + 1] = v.y;
    }

    // ---- A fragments: tile i = gate-rows [16i,16i+16), k-half kk.
    // Layout: lane holds A[m=cl][k=8*qd+j], j=0..7  (16x16x32 f16 A-operand).
    f16x8 afrag[16][2];
    #pragma unroll
    for (int i = 0; i < 16; ++i) {
        #pragma unroll
        for (int kk = 0; kk < 2; ++kk) {
            const float* src = W_hh + (size_t)(16 * i + cl) * HID + 32 * kk + 8 * qd;
            const float4 lo = *(const float4*)(src);
            const float4 hi = *(const float4*)(src + 4);
            f16x8 a;
            a[0] = (f16)lo.x; a[1] = (f16)lo.y; a[2] = (f16)lo.z; a[3] = (f16)lo.w;
            a[4] = (f16)hi.x; a[5] = (f16)hi.y; a[6] = (f16)hi.z; a[7] = (f16)hi.w;
            afrag[i][kk] = a;
        }
    }

    // ---- per-unit (lane) bias + input weights (unit = lane after epilogue)
    const float bs0 = b_ih[0*HID + lane] + b_hh[0*HID + lane];
    const float bs1 = b_ih[1*HID + lane] + b_hh[1*HID + lane];
    const float bs2 = b_ih[2*HID + lane] + b_hh[2*HID + lane];
    const float bs3 = b_ih[3*HID + lane] + b_hh[3*HID + lane];
    const float wiA0 = W_ih[(0*HID + lane)*2], wiB0 = W_ih[(0*HID + lane)*2 + 1];
    const float wiA1 = W_ih[(1*HID + lane)*2], wiB1 = W_ih[(1*HID + lane)*2 + 1];
    const float wiA2 = W_ih[(2*HID + lane)*2], wiB2 = W_ih[(2*HID + lane)*2 + 1];
    const float wiA3 = W_ih[(3*HID + lane)*2], wiB3 = W_ih[(3*HID + lane)*2 + 1];

    float hval = 0.0f;              // lane l owns unit l
    float cval = 0.0f;
    hfrag[0][lane] = (f16)0.0f;     // t=0 reads buffer 0 (same-wave DS order)

    const f32x4 zero = {0.0f, 0.0f, 0.0f, 0.0f};

    for (int t = 0; t < T_LEN; ++t) {
        const int b = t & 1;

        // ---- B-fragments: lane holds B[k=8*qd+j][n=cl] = h_f16[32*kk+8*qd+j]
        const char* hbase = (const char*)&hfrag[b][0];
        const f16x8 bf0 = *(const f16x8*)(hbase + 16 * qd);        // k 0..31
        const f16x8 bf1 = *(const f16x8*)(hbase + 64 + 16 * qd);   // k 32..63

        const float2 xv = *(const float2*)(xs + 2 * t);  // uniform bcast

        // ---- 32 MFMAs: acc[i] = Wtile(i) @ h  (16 indep 2-chains)
        f32x4 acc[16];
        #pragma unroll
        for (int i = 0; i < 16; ++i)
            acc[i] = __builtin_amdgcn_mfma_f32_16x16x32_f16(afrag[i][0], bf0, zero, 0, 0, 0);
        #pragma unroll
        for (int i = 0; i < 16; ++i)
            acc[i] = __builtin_amdgcn_mfma_f32_16x16x32_f16(afrag[i][1], bf1, acc[i], 0, 0, 0);

        // bias + x contribution (independent of h — overlaps MFMA phase)
        const float xb0 = fmaf(wiA0, xv.x, fmaf(wiB0, xv.y, bs0));
        const float xb1 = fmaf(wiA1, xv.x, fmaf(wiB1, xv.y, bs1));
        const float xb2 = fmaf(wiA2, xv.x, fmaf(wiB2, xv.y, bs2));
        const float xb3 = fmaf(wiA3, xv.x, fmaf(wiB3, xv.y, bs3));

        // ---- epilogue scatter: col-0 lanes (4 active) hold rows 16i+4qd+r of
        // every tile i => global row R=16i+4qd+r => gate=i>>2, unit=16(i&3)+4qd+r
        if (cl == 0) {
            #pragma unroll
            for (int i = 0; i < 16; ++i)
                *(f32x4*)&glds[b][i >> 2][16 * (i & 3) + 4 * qd] = acc[i];
        }

        // ---- gather my unit's 4 gates (consecutive addr, conflict-free;
        // same-wave DS FIFO => writes complete before these reads return)
        const float gi = fast_sigmoid(glds[b][0][lane] + xb0);
        const float gf = fast_sigmoid(glds[b][1][lane] + xb1);
        const float gg = fast_tanh   (glds[b][2][lane] + xb2);
        const float go = fast_sigmoid(glds[b][3][lane] + xb3);

        cval = fmaf(gf, cval, gi * gg);
        hval = go * fast_tanh(cval);

        // h history: fire-and-forget coalesced store (off the serial chain)
        hist[t * HID + lane] = hval;

        // publish h(t) in f16 for next step's B-frag
        hfrag[(t + 1) & 1][lane] = (f16)hval;
    }

    // ---- projection: out[t,o] = b_fc[o] + dot(W_fc[o,:], hist[t,:])
    // (same-wave store->load on hist: compiler orders via vmcnt)
    for (int jj = 0; jj < 32; ++jj) {
        const int idx = lane + 64 * jj;     // 0..2047
        const int tt  = idx >> 1;
        const int o   = idx & 1;
        const float4* hv4 = (const float4*)(hist + tt * HID);
        const float4* wv  = (const float4*)(W_fc + o * HID);
        float p0 = 0.f, p1 = 0.f, p2 = 0.f, p3 = 0.f;
        #pragma unroll
        for (int k = 0; k < HID / 4; ++k) {
            const float4 h4 = hv4[k], w4 = wv[k];
            p0 = fmaf(h4.x, w4.x, p0);
            p1 = fmaf(h4.y, w4.y, p1);
            p2 = fmaf(h4.z, w4.z, p2);
            p3 = fmaf(h4.w, w4.w, p3);
        }
        out[idx] = b_fc[o] + ((p0 + p1) + (p2 + p3));
    }
}

extern "C" void kernel_launch(void* const* d_in, const int* in_sizes, int n_in,
                              void* d_out, int out_size, void* d_ws, size_t ws_size,
                              hipStream_t stream) {
    const float* x    = (const float*)d_in[0];
    const float* W_ih = (const float*)d_in[1];
    const float* W_hh = (const float*)d_in[2];
    const float* b_ih = (const float*)d_in[3];
    const float* b_hh = (const float*)d_in[4];
    const float* W_fc = (const float*)d_in[5];
    const float* b_fc = (const float*)d_in[6];
    float* out  = (float*)d_out;
    float* hist = (float*)d_ws;   // needs 1024*64*4 = 256 KB

    lstm_seq_kernel<<<dim3(1), dim3(64), 0, stream>>>(
        x, W_ih, W_hh, b_ih, b_hh, W_fc, b_fc, out, hist);
}

// Round 8
// 763.178 us; speedup vs baseline: 1.0490x; 1.0490x over previous
//
#include <hip/hip_runtime.h>

// LSTM RNN_20263655702953 — MI355X (gfx950), round 8.
//
// Reference quirk: hs[:, -1, :] selects BATCH index 511 => single sequential
// LSTM chain (1024 steps, H=64), then (1024,64)@(64,2) projection.
//
// R8: single-wave f16 MFMA (R7) minus the two measured pathologies:
//  (1) R7's LDS scatter/gather epilogue (16 ds_write_b128 + FIFO-ordered
//      reads, ~250 DS cyc on the serial chain) is replaced by a pure-VALU
//      select enabled by ROW-REMAPPED tiles: tile i, A-row m carries global
//      row 64*(m&3) + 16*(m>>2) + i. With h replicated over B-cols, lane
//      u=(q<<4)|cl then holds G[64g+16q+i] in acc[i] component g, so its
//      unit's gates are acc[cl][*]: a 16-way v_cndmask select on the
//      loop-invariant cond (cl==i) (LICM -> 16 SGPR masks, 60 cndmask/step).
//  (2) R7's AGPR shuffling (VGPR=140 => compiler pushed afrag/acc to AGPRs,
//      ~250 v_accvgpr moves/step): selects are folded into the tile loop so
//      each acc dies immediately — peak live ~170 VGPRs, all-VGPR fit.
// No barriers (single wave); all LDS same-wave; hist stores fire-and-forget.

typedef _Float16 f16;
typedef _Float16 f16x8 __attribute__((ext_vector_type(8)));
typedef float    f32x4 __attribute__((ext_vector_type(4)));

#define T_LEN 1024
#define BATCH 512
#define HID   64

__device__ __forceinline__ float fast_rcp(float x) {
    return __builtin_amdgcn_rcpf(x);  // v_rcp_f32, ~1e-7 rel err
}
__device__ __forceinline__ float fast_sigmoid(float x) {
    return fast_rcp(1.0f + __expf(-x));
}
__device__ __forceinline__ float fast_tanh(float x) {
    // 1 - 2/(e^{2x}+1); saturates correctly for |x| large
    return 1.0f - 2.0f * fast_rcp(__expf(2.0f * x) + 1.0f);
}

__global__ __launch_bounds__(64, 1)
void lstm_seq_kernel(const float* __restrict__ x,
                     const float* __restrict__ W_ih,
                     const float* __restrict__ W_hh,
                     const float* __restrict__ b_ih,
                     const float* __restrict__ b_hh,
                     const float* __restrict__ W_fc,
                     const float* __restrict__ b_fc,
                     float* __restrict__ out,
                     float* __restrict__ hist)   // d_ws: 1024*64 floats
{
    __shared__ __align__(16) float xs[2 * T_LEN];   // 8 KB: x[:,511,:]
    __shared__ __align__(16) f16   hfrag[2][HID];   // 256 B: h in f16, dbuf

    const int lane = threadIdx.x;   // 0..63
    const int qd   = lane >> 4;     // quad group 0..3 (k-block of A/B)
    const int cl   = lane & 15;     // col 0..15 (A m-row; selects tile)

    // ---- stage x[:,511,:] into LDS (one-time; same-wave => no barrier)
    for (int j = 0; j < 16; ++j) {
        const int t = lane + 64 * j;
        const float2 v = *(const float2*)(x + (size_t)(t * BATCH + (BATCH - 1)) * 2);
        xs[2 * t]     = v.x;
        xs[2 * t + 1] = v.y;
    }

    // ---- A fragments, ROW-REMAPPED: tile i, A-row m holds global row
    // R(i,m) = 64*(m&3) + 16*(m>>2) + i.  Lane loads m = cl:
    //   row = 64*(cl&3) + 16*(cl>>2) + i, k = 32*kk + 8*qd + j.
    // After MFMA, acc[i] reg g in lane (q<<4|cl) = G[64g + 16q + i].
    f16x8 afrag[16][2];
    {
        const int grow = 64 * (cl & 3) + 16 * (cl >> 2);
        #pragma unroll
        for (int i = 0; i < 16; ++i) {
            #pragma unroll
            for (int kk = 0; kk < 2; ++kk) {
                const float* src = W_hh + (size_t)(grow + i) * HID + 32 * kk + 8 * qd;
                const float4 lo = *(const float4*)(src);
                const float4 hi = *(const float4*)(src + 4);
                f16x8 a;
                a[0] = (f16)lo.x; a[1] = (f16)lo.y; a[2] = (f16)lo.z; a[3] = (f16)lo.w;
                a[4] = (f16)hi.x; a[5] = (f16)hi.y; a[6] = (f16)hi.z; a[7] = (f16)hi.w;
                afrag[i][kk] = a;
            }
        }
    }

    // ---- per-unit (lane) bias + input weights (unit == lane)
    const float bs0 = b_ih[0*HID + lane] + b_hh[0*HID + lane];
    const float bs1 = b_ih[1*HID + lane] + b_hh[1*HID + lane];
    const float bs2 = b_ih[2*HID + lane] + b_hh[2*HID + lane];
    const float bs3 = b_ih[3*HID + lane] + b_hh[3*HID + lane];
    const float wiA0 = W_ih[(0*HID + lane)*2], wiB0 = W_ih[(0*HID + lane)*2 + 1];
    const float wiA1 = W_ih[(1*HID + lane)*2], wiB1 = W_ih[(1*HID + lane)*2 + 1];
    const float wiA2 = W_ih[(2*HID + lane)*2], wiB2 = W_ih[(2*HID + lane)*2 + 1];
    const float wiA3 = W_ih[(3*HID + lane)*2], wiB3 = W_ih[(3*HID + lane)*2 + 1];

    float hval = 0.0f;              // lane l owns unit l
    float cval = 0.0f;
    hfrag[0][lane] = (f16)0.0f;     // t=0 reads buffer 0 (same-wave DS order)

    const f32x4 zero = {0.0f, 0.0f, 0.0f, 0.0f};

    for (int t = 0; t < T_LEN; ++t) {
        const int b = t & 1;

        // ---- B-fragments: h replicated over the 16 cols.
        // lane holds B[k=8*qd+j][n=cl] = h_f16[32*kk + 8*qd + j]
        const char* hbase = (const char*)&hfrag[b][0];
        const f16x8 bf0 = *(const f16x8*)(hbase + 16 * qd);        // k 0..31
        const f16x8 bf1 = *(const f16x8*)(hbase + 64 + 16 * qd);   // k 32..63

        const float2 xv = *(const float2*)(xs + 2 * t);  // uniform bcast

        // ---- 16 tiles x 2 MFMAs, each acc consumed immediately by the
        // running select (cond cl==i is loop-invariant -> SGPR masks).
        f32x4 gsel;
        #pragma unroll
        for (int i = 0; i < 16; ++i) {
            f32x4 acc = __builtin_amdgcn_mfma_f32_16x16x32_f16(afrag[i][0], bf0, zero, 0, 0, 0);
            acc = __builtin_amdgcn_mfma_f32_16x16x32_f16(afrag[i][1], bf1, acc,  0, 0, 0);
            if (i == 0) {
                gsel = acc;
            } else {
                const bool m = (cl == i);
                gsel.x = m ? acc.x : gsel.x;
                gsel.y = m ? acc.y : gsel.y;
                gsel.z = m ? acc.z : gsel.z;
                gsel.w = m ? acc.w : gsel.w;
            }
        }

        // bias + x contribution (independent of h — overlaps MFMA phase)
        const float xb0 = fmaf(wiA0, xv.x, fmaf(wiB0, xv.y, bs0));
        const float xb1 = fmaf(wiA1, xv.x, fmaf(wiB1, xv.y, bs1));
        const float xb2 = fmaf(wiA2, xv.x, fmaf(wiB2, xv.y, bs2));
        const float xb3 = fmaf(wiA3, xv.x, fmaf(wiB3, xv.y, bs3));

        // ---- lane-local activations + state update
        const float gi = fast_sigmoid(gsel.x + xb0);
        const float gf = fast_sigmoid(gsel.y + xb1);
        const float gg = fast_tanh   (gsel.z + xb2);
        const float go = fast_sigmoid(gsel.w + xb3);

        cval = fmaf(gf, cval, gi * gg);
        hval = go * fast_tanh(cval);

        // h history: fire-and-forget coalesced store (off the serial chain;
        // 1 store/step never exhausts the vmcnt queue)
        hist[t * HID + lane] = hval;

        // publish h(t) in f16 for next step's B-frag (same-wave DS order)
        hfrag[(t + 1) & 1][lane] = (f16)hval;
    }

    // ---- projection: out[t,o] = b_fc[o] + dot(W_fc[o,:], hist[t,:])
    // (same-wave store->load on hist: compiler orders via vmcnt)
    for (int jj = 0; jj < 32; ++jj) {
        const int idx = lane + 64 * jj;     // 0..2047
        const int tt  = idx >> 1;
        const int o   = idx & 1;
        const float4* hv4 = (const float4*)(hist + tt * HID);
        const float4* wv  = (const float4*)(W_fc + o * HID);
        float p0 = 0.f, p1 = 0.f, p2 = 0.f, p3 = 0.f;
        #pragma unroll
        for (int k = 0; k < HID / 4; ++k) {
            const float4 h4 = hv4[k], w4 = wv[k];
            p0 = fmaf(h4.x, w4.x, p0);
            p1 = fmaf(h4.y, w4.y, p1);
            p2 = fmaf(h4.z, w4.z, p2);
            p3 = fmaf(h4.w, w4.w, p3);
        }
        out[idx] = b_fc[o] + ((p0 + p1) + (p2 + p3));
    }
}

extern "C" void kernel_launch(void* const* d_in, const int* in_sizes, int n_in,
                              void* d_out, int out_size, void* d_ws, size_t ws_size,
                              hipStream_t stream) {
    const float* x    = (const float*)d_in[0];
    const float* W_ih = (const float*)d_in[1];
    const float* W_hh = (const float*)d_in[2];
    const float* b_ih = (const float*)d_in[3];
    const float* b_hh = (const float*)d_in[4];
    const float* W_fc = (const float*)d_in[5];
    const float* b_fc = (const float*)d_in[6];
    float* out  = (float*)d_out;
    float* hist = (float*)d_ws;   // needs 1024*64*4 = 256 KB

    lstm_seq_kernel<<<dim3(1), dim3(64), 0, stream>>>(
        x, W_ih, W_hh, b_ih, b_hh, W_fc, b_fc, out, hist);
}

// Round 9
// 504.538 us; speedup vs baseline: 1.5868x; 1.5126x over previous
//
#include <hip/hip_runtime.h>

// LSTM RNN_20263655702953 — MI355X (gfx950), round 9.
//
// Reference quirk: hs[:, -1, :] selects BATCH index 511 => single sequential
// LSTM chain (1024 steps, H=64), then (1024,64)@(64,2) projection.
//
// R9: single-wave MFMA with (1) weights pinned in AGPRs via inline-asm
// "a"-constraint MFMA (MAI reads AGPR operands natively; kills R7/R8's
// ~256 v_accvgpr moves/step, measured as 600 phantom VALU cyc) and
// (2) TRANSPOSED formulation: A = h replicated over rows, B = W^T tile i
// => D[r][c] = G[16i+c] replicated over rows. Every lane holds G[16i+cl]
// per tile; unit u=16q+cl's gate g sits in tile 4g+q => extraction is
// 12 v_cndmask on loop-invariant q (vs 60 in R8), no LDS epilogue.
// All 32 MFMAs issue as 16 independent 2-chains (16 firsts, then 16
// seconds), then ONE manual 19-cyc s_nop hazard block (compiler can't see
// MFMA inside asm => must pay MFMA->VALU wait manually), then selects.
// Single wave => no barriers; single-buffer hfr LDS (read-top/write-bottom,
// same-wave DS FIFO + lgkmcnt ordering).

typedef _Float16 f16;
typedef float f32x4 __attribute__((ext_vector_type(4)));
typedef int   i32x4 __attribute__((ext_vector_type(4)));

#define T_LEN 1024
#define BATCH 512
#define HID   64

__device__ __forceinline__ float fast_rcp(float x) {
    return __builtin_amdgcn_rcpf(x);
}
__device__ __forceinline__ float fast_sigmoid(float x) {
    return fast_rcp(1.0f + __expf(-x));
}
__device__ __forceinline__ float fast_tanh(float x) {
    return 1.0f - 2.0f * fast_rcp(__expf(2.0f * x) + 1.0f);
}

// D = A*B + C, B held in AGPRs (MAI reads AGPR sources natively)
__device__ __forceinline__ f32x4 mfma_z(i32x4 a, i32x4 b, f32x4 z) {
    f32x4 d;
    asm volatile("v_mfma_f32_16x16x32_f16 %0, %1, %2, %3"
                 : "=v"(d) : "v"(a), "a"(b), "v"(z));
    return d;
}
__device__ __forceinline__ void mfma_acc(f32x4& d, i32x4 a, i32x4 b) {
    asm volatile("v_mfma_f32_16x16x32_f16 %0, %1, %2, %0"
                 : "+v"(d) : "v"(a), "a"(b));
}

__global__ __launch_bounds__(64, 1)
void lstm_seq_kernel(const float* __restrict__ x,
                     const float* __restrict__ W_ih,
                     const float* __restrict__ W_hh,
                     const float* __restrict__ b_ih,
                     const float* __restrict__ b_hh,
                     const float* __restrict__ W_fc,
                     const float* __restrict__ b_fc,
                     float* __restrict__ out,
                     float* __restrict__ hist)   // d_ws: 1024*64 floats
{
    __shared__ __align__(16) float xs[2 * T_LEN];  // 8 KB: x[:,511,:]
    __shared__ __align__(16) f16   hfr[HID];       // 128 B: h in f16

    const int lane = threadIdx.x;   // 0..63
    const int q    = lane >> 4;     // quad group 0..3
    const int cl   = lane & 15;     // col 0..15

    // ---- stage x[:,511,:] into LDS (one-time; same-wave => no barrier)
    for (int j = 0; j < 16; ++j) {
        const int t = lane + 64 * j;
        const float2 v = *(const float2*)(x + (size_t)(t * BATCH + (BATCH - 1)) * 2);
        xs[2 * t]     = v.x;
        xs[2 * t + 1] = v.y;
    }

    // ---- W^T B-fragments, destined for AGPRs (only ever used via "a"):
    // tile i, k-half kk: lane(q,cl) holds B[k=8q+j][n=cl] = W_hh[16i+cl][32kk+8q+j]
    i32x4 wf[16][2];
    #pragma unroll
    for (int i = 0; i < 16; ++i) {
        #pragma unroll
        for (int kk = 0; kk < 2; ++kk) {
            const float* src = W_hh + (size_t)(16 * i + cl) * HID + 32 * kk + 8 * q;
            union { f16 h[8]; i32x4 v; } p;
            #pragma unroll
            for (int j = 0; j < 8; ++j) p.h[j] = (f16)src[j];
            wf[i][kk] = p.v;
        }
    }

    // ---- per-unit (lane) bias + input weights (unit == lane)
    const float bs0 = b_ih[0*HID + lane] + b_hh[0*HID + lane];
    const float bs1 = b_ih[1*HID + lane] + b_hh[1*HID + lane];
    const float bs2 = b_ih[2*HID + lane] + b_hh[2*HID + lane];
    const float bs3 = b_ih[3*HID + lane] + b_hh[3*HID + lane];
    const float wiA0 = W_ih[(0*HID + lane)*2], wiB0 = W_ih[(0*HID + lane)*2 + 1];
    const float wiA1 = W_ih[(1*HID + lane)*2], wiB1 = W_ih[(1*HID + lane)*2 + 1];
    const float wiA2 = W_ih[(2*HID + lane)*2], wiB2 = W_ih[(2*HID + lane)*2 + 1];
    const float wiA3 = W_ih[(3*HID + lane)*2], wiB3 = W_ih[(3*HID + lane)*2 + 1];

    const bool q1 = (q == 1), q2 = (q == 2), q3 = (q == 3);

    float hval = 0.0f;              // lane l owns unit l
    float cval = 0.0f;
    hfr[lane] = (f16)0.0f;          // t=0 reads this (same-wave DS order)

    const f32x4 zq = {0.0f, 0.0f, 0.0f, 0.0f};
    const char* hb = (const char*)hfr;

    // insurance: cover any late v->a weight copies before first MFMA
    asm volatile("s_nop 7\n\ts_nop 7");

    #pragma clang loop unroll(disable)
    for (int t = 0; t < T_LEN; ++t) {
        // A-frags: h replicated over rows — lane needs h[32kk+8q..+7] as f16x8
        const i32x4 alo = *(const i32x4*)(hb + 16 * q);        // k 0..31
        const i32x4 ahi = *(const i32x4*)(hb + 64 + 16 * q);   // k 32..63
        const float2 xv = *(const float2*)(xs + 2 * t);        // uniform bcast

        // ---- 16 independent 2-chains; program order fixed by volatile asm:
        // 16 firsts (independent, pipeline fills), then 16 seconds.
        f32x4 d0,d1,d2,d3,d4,d5,d6,d7,d8,d9,d10,d11,d12,d13,d14,d15;
        d0  = mfma_z(alo, wf[0][0],  zq);  d1  = mfma_z(alo, wf[1][0],  zq);
        d2  = mfma_z(alo, wf[2][0],  zq);  d3  = mfma_z(alo, wf[3][0],  zq);
        d4  = mfma_z(alo, wf[4][0],  zq);  d5  = mfma_z(alo, wf[5][0],  zq);
        d6  = mfma_z(alo, wf[6][0],  zq);  d7  = mfma_z(alo, wf[7][0],  zq);
        d8  = mfma_z(alo, wf[8][0],  zq);  d9  = mfma_z(alo, wf[9][0],  zq);
        d10 = mfma_z(alo, wf[10][0], zq);  d11 = mfma_z(alo, wf[11][0], zq);
        d12 = mfma_z(alo, wf[12][0], zq);  d13 = mfma_z(alo, wf[13][0], zq);
        d14 = mfma_z(alo, wf[14][0], zq);  d15 = mfma_z(alo, wf[15][0], zq);
        mfma_acc(d0,  ahi, wf[0][1]);   mfma_acc(d1,  ahi, wf[1][1]);
        mfma_acc(d2,  ahi, wf[2][1]);   mfma_acc(d3,  ahi, wf[3][1]);
        mfma_acc(d4,  ahi, wf[4][1]);   mfma_acc(d5,  ahi, wf[5][1]);
        mfma_acc(d6,  ahi, wf[6][1]);   mfma_acc(d7,  ahi, wf[7][1]);
        mfma_acc(d8,  ahi, wf[8][1]);   mfma_acc(d9,  ahi, wf[9][1]);
        mfma_acc(d10, ahi, wf[10][1]);  mfma_acc(d11, ahi, wf[11][1]);
        mfma_acc(d12, ahi, wf[12][1]);  mfma_acc(d13, ahi, wf[13][1]);
        mfma_acc(d14, ahi, wf[14][1]);  mfma_acc(d15, ahi, wf[15][1]);

        // bias + x (independent of h — scheduled into the MFMA shadow)
        const float xb0 = fmaf(wiA0, xv.x, fmaf(wiB0, xv.y, bs0));
        const float xb1 = fmaf(wiA1, xv.x, fmaf(wiB1, xv.y, bs1));
        const float xb2 = fmaf(wiA2, xv.x, fmaf(wiB2, xv.y, bs2));
        const float xb3 = fmaf(wiA3, xv.x, fmaf(wiB3, xv.y, bs3));

        // ---- ONE manual MFMA->VALU hazard gap; ties all accs so the
        // selects below cannot be scheduled into the hazard window.
        asm volatile("s_nop 7\n\ts_nop 7\n\ts_nop 2"
                     : "+v"(d0), "+v"(d1), "+v"(d2),  "+v"(d3),
                       "+v"(d4), "+v"(d5), "+v"(d6),  "+v"(d7),
                       "+v"(d8), "+v"(d9), "+v"(d10), "+v"(d11),
                       "+v"(d12),"+v"(d13),"+v"(d14), "+v"(d15));

        // ---- extraction: lane(q,cl) = unit 16q+cl; gate g is in tile 4g+q,
        // value replicated across acc regs => read .x; 3 cndmask per gate.
        float s0 = d0.x;  s0 = q1 ? d1.x  : s0; s0 = q2 ? d2.x  : s0; s0 = q3 ? d3.x  : s0;
        float s1 = d4.x;  s1 = q1 ? d5.x  : s1; s1 = q2 ? d6.x  : s1; s1 = q3 ? d7.x  : s1;
        float s2 = d8.x;  s2 = q1 ? d9.x  : s2; s2 = q2 ? d10.x : s2; s2 = q3 ? d11.x : s2;
        float s3 = d12.x; s3 = q1 ? d13.x : s3; s3 = q2 ? d14.x : s3; s3 = q3 ? d15.x : s3;

        // ---- lane-local activations + state update (unit u = 16q+cl ==
        // consistent with per-lane bias iff lane == 16q+cl: true by defn)
        const float gi = fast_sigmoid(s0 + xb0);
        const float gf = fast_sigmoid(s1 + xb1);
        const float gg = fast_tanh   (s2 + xb2);
        const float go = fast_sigmoid(s3 + xb3);

        cval = fmaf(gf, cval, gi * gg);
        hval = go * fast_tanh(cval);

        // h history: fire-and-forget coalesced store (off the serial chain)
        hist[t * HID + lane] = hval;

        // publish h(t) for next step's A-frags (same-wave DS ordering)
        hfr[lane] = (f16)hval;
    }

    // ---- projection: out[t,o] = b_fc[o] + dot(W_fc[o,:], hist[t,:])
    // (same-wave store->load on hist: compiler orders via vmcnt)
    for (int jj = 0; jj < 32; ++jj) {
        const int idx = lane + 64 * jj;     // 0..2047
        const int tt  = idx >> 1;
        const int o   = idx & 1;
        const float4* hv4 = (const float4*)(hist + tt * HID);
        const float4* wv  = (const float4*)(W_fc + o * HID);
        float p0 = 0.f, p1 = 0.f, p2 = 0.f, p3 = 0.f;
        #pragma unroll
        for (int k = 0; k < HID / 4; ++k) {
            const float4 h4 = hv4[k], w4 = wv[k];
            p0 = fmaf(h4.x, w4.x, p0);
            p1 = fmaf(h4.y, w4.y, p1);
            p2 = fmaf(h4.z, w4.z, p2);
            p3 = fmaf(h4.w, w4.w, p3);
        }
        out[idx] = b_fc[o] + ((p0 + p1) + (p2 + p3));
    }
}

extern "C" void kernel_launch(void* const* d_in, const int* in_sizes, int n_in,
                              void* d_out, int out_size, void* d_ws, size_t ws_size,
                              hipStream_t stream) {
    const float* x    = (const float*)d_in[0];
    const float* W_ih = (const float*)d_in[1];
    const float* W_hh = (const float*)d_in[2];
    const float* b_ih = (const float*)d_in[3];
    const float* b_hh = (const float*)d_in[4];
    const float* W_fc = (const float*)d_in[5];
    const float* b_fc = (const float*)d_in[6];
    float* out  = (float*)d_out;
    float* hist = (float*)d_ws;   // needs 1024*64*4 = 256 KB

    lstm_seq_kernel<<<dim3(1), dim3(64), 0, stream>>>(
        x, W_ih, W_hh, b_ih, b_hh, W_fc, b_fc, out, hist);
}